// Round 1
// baseline (15514.333 us; speedup 1.0000x reference)
//
#include <hip/hip_runtime.h>

// Problem constants
constexpr int B_ = 32, S_ = 300, D_ = 512, H_ = 8;
constexpr int L_ = 6, E_ = 6, F_ = 1024;
constexpr int CHORD_ = 159;
constexpr int R_ = B_ * S_;      // 9600 rows (tokens)
constexpr int TD_ = 3 * D_;      // 1536
constexpr int MT_ = R_ / 64;     // 150 row tiles per expert (worst case)
constexpr size_t WSCAP_ = (size_t)E_ * F_ * 512;  // 3,145,728 shorts per weight-scratch buffer

typedef short bfrag __attribute__((ext_vector_type(8)));   // 8 bf16 bit-patterns (4 VGPRs)
typedef float facc  __attribute__((ext_vector_type(4)));   // MFMA accumulator

static __device__ __forceinline__ facc mfma_(bfrag a, bfrag b, facc c) {
    return __builtin_amdgcn_mfma_f32_16x16x32_bf16(a, b, c, 0, 0, 0);
}

// float -> bf16 (RNE) bit pattern
static __device__ __forceinline__ short f2bf_rne(float f) {
    unsigned u = __float_as_uint(f);
    return (short)((u + 0x7FFFu + ((u >> 16) & 1u)) >> 16);
}
// split x into hi (truncated bf16) + lo (RNE bf16 of remainder); x ~= hi + lo to ~2^-17 rel
static __device__ __forceinline__ void split2(float x, short& hi, short& lo) {
    unsigned u = __float_as_uint(x);
    hi = (short)(u >> 16);
    float fh = __uint_as_float(u & 0xFFFF0000u);
    lo = f2bf_rne(x - fh);
}

// ---------------- block reduction (sum, sumsq) over 256 threads ----------------
static __device__ __forceinline__ float2 blockReduce2(float s, float ss) {
    __shared__ float red[4][2];
    #pragma unroll
    for (int o = 32; o > 0; o >>= 1) { s += __shfl_down(s, o); ss += __shfl_down(ss, o); }
    const int wid = threadIdx.x >> 6, lane = threadIdx.x & 63;
    if (lane == 0) { red[wid][0] = s; red[wid][1] = ss; }
    __syncthreads();
    if (threadIdx.x == 0) {
        for (int w = 1; w < 4; ++w) { s += red[w][0]; ss += red[w][1]; }
        red[0][0] = s; red[0][1] = ss;
    }
    __syncthreads();
    return make_float2(red[0][0], red[0][1]);
}

// ---------------- weight split (row-major [N][K] f32 -> [N][Kp] bf16 hi/lo, zero pad) ----------------
__global__ void wsplit_kern(const float* __restrict__ src, short* __restrict__ dh, short* __restrict__ dl,
                            int N, int K, int Kp)
{
    const int idx = blockIdx.x * 256 + threadIdx.x;
    if (idx >= N * Kp) return;
    const int n = idx / Kp, k = idx - n * Kp;
    const float v = (k < K) ? src[(size_t)n * K + k] : 0.f;
    short sh, sl; split2(v, sh, sl);
    dh[idx] = sh; dl[idx] = sl;
}

// ---------------- transpose-split: src [E][K][N] f32 -> dst [E][N][K] bf16 hi/lo ----------------
// K, N multiples of 32. grid = (K/32, N/32, E), block 256.
__global__ __launch_bounds__(256) void tsplit_kern(const float* __restrict__ src,
                                                   short* __restrict__ dh, short* __restrict__ dl,
                                                   int K, int N)
{
    __shared__ float tile[32][33];
    const size_t eo = (size_t)blockIdx.z * K * N;
    const float* s = src + eo;
    short* oh = dh + eo;
    short* ol = dl + eo;
    const int kb = blockIdx.x * 32, nb = blockIdx.y * 32;
    const int c = threadIdx.x & 31, r0 = threadIdx.x >> 5;
    #pragma unroll
    for (int p = 0; p < 4; ++p) {
        const int r = r0 + p * 8;
        tile[r][c] = s[(size_t)(kb + r) * N + nb + c];
    }
    __syncthreads();
    #pragma unroll
    for (int p = 0; p < 4; ++p) {
        const int wn = r0 + p * 8;
        const float v = tile[c][wn];
        short sh, sl; split2(v, sh, sl);
        const size_t o = (size_t)(nb + wn) * K + kb + c;
        oh[o] = sh; ol[o] = sl;
    }
}

// ---------------- split-bf16 MFMA GEMM: Y[m,n] = sum_k X[m,k]*W[n,k] + bias (+pos) ----------------
// X split: Xh/Xl [R_][Kp] bf16; W split: Wh/Wl [N][Kp] bf16 (zero-padded). Tile 64x128, 2 waves.
__global__ __launch_bounds__(128) void gemm_mfma(
    const short* __restrict__ Xh, const short* __restrict__ Xl,
    const short* __restrict__ Wh, const short* __restrict__ Wl, int Kp,
    const float* __restrict__ bias, const float* __restrict__ pos,
    float* __restrict__ Y, int ldy, int N,
    short* __restrict__ Yh, short* __restrict__ Yl)
{
    __shared__ __align__(16) short Ah[64][40], Al[64][40];
    __shared__ __align__(16) short Bh[128][40], Bl[128][40];
    const int m0 = blockIdx.x * 64, n0 = blockIdx.y * 128;
    const int tid = threadIdx.x;
    const int w = tid >> 6, l = tid & 63;
    const facc zero = {0.f, 0.f, 0.f, 0.f};
    facc acc[4][4];
    #pragma unroll
    for (int i = 0; i < 4; ++i)
        #pragma unroll
        for (int j = 0; j < 4; ++j) acc[i][j] = zero;
    const int ar = tid >> 2, aks = (tid & 3) * 8;
    const int bcol = tid;
    const bool bok = (n0 + bcol) < N;
    const size_t bbase = (size_t)(n0 + bcol) * Kp;
    const bfrag zf = {0, 0, 0, 0, 0, 0, 0, 0};
    for (int kc = 0; kc < Kp; kc += 32) {
        #pragma unroll
        for (int p = 0; p < 2; ++p) {
            const int row = ar + p * 32;
            const size_t go = (size_t)(m0 + row) * Kp + kc + aks;
            *(bfrag*)&Ah[row][aks] = *(const bfrag*)&Xh[go];
            *(bfrag*)&Al[row][aks] = *(const bfrag*)&Xl[go];
        }
        if (bok) {
            #pragma unroll
            for (int i2 = 0; i2 < 4; ++i2) {
                *(bfrag*)&Bh[bcol][i2 * 8] = *(const bfrag*)&Wh[bbase + kc + i2 * 8];
                *(bfrag*)&Bl[bcol][i2 * 8] = *(const bfrag*)&Wl[bbase + kc + i2 * 8];
            }
        } else {
            #pragma unroll
            for (int i2 = 0; i2 < 4; ++i2) {
                *(bfrag*)&Bh[bcol][i2 * 8] = zf;
                *(bfrag*)&Bl[bcol][i2 * 8] = zf;
            }
        }
        __syncthreads();
        bfrag ah[4], al[4];
        #pragma unroll
        for (int i2 = 0; i2 < 4; ++i2) {
            ah[i2] = *(const bfrag*)&Ah[i2 * 16 + (l & 15)][(l >> 4) * 8];
            al[i2] = *(const bfrag*)&Al[i2 * 16 + (l & 15)][(l >> 4) * 8];
        }
        #pragma unroll
        for (int j = 0; j < 4; ++j) {
            const int cc = w * 64 + j * 16 + (l & 15);
            const bfrag bh = *(const bfrag*)&Bh[cc][(l >> 4) * 8];
            const bfrag bl = *(const bfrag*)&Bl[cc][(l >> 4) * 8];
            #pragma unroll
            for (int i2 = 0; i2 < 4; ++i2) {
                acc[i2][j] = mfma_(ah[i2], bh, acc[i2][j]);
                acc[i2][j] = mfma_(al[i2], bh, acc[i2][j]);
                acc[i2][j] = mfma_(ah[i2], bl, acc[i2][j]);
            }
        }
        __syncthreads();
    }
    #pragma unroll
    for (int i2 = 0; i2 < 4; ++i2) {
        #pragma unroll
        for (int r = 0; r < 4; ++r) {
            const int m = m0 + i2 * 16 + (l >> 4) * 4 + r;
            #pragma unroll
            for (int j = 0; j < 4; ++j) {
                const int n = n0 + w * 64 + j * 16 + (l & 15);
                if (n < N) {
                    float y = acc[i2][j][r];
                    if (bias) y += bias[n];
                    if (pos)  y += pos[(size_t)(m % S_) * N + n];
                    Y[(size_t)m * ldy + n] = y;
                    if (Yh) {
                        short sh, sl; split2(y, sh, sl);
                        Yh[(size_t)m * ldy + n] = sh;
                        Yl[(size_t)m * ldy + n] = sl;
                    }
                }
            }
        }
    }
}

// ---------------- fused attention, single-pass online softmax; writes bf16 split output ----------------
template<bool CAUSAL>
__global__ __launch_bounds__(320) void attn_kern(const float* __restrict__ qkv,
                                                 short* __restrict__ oh, short* __restrict__ ol)
{
    __shared__ float Ks[64][64];
    __shared__ float Vs[64][64];
    const int b = blockIdx.x >> 3, hh = blockIdx.x & 7;
    const int tid = threadIdx.x;
    const float* base = qkv + (size_t)b * S_ * TD_ + hh * 64;
    const bool act = tid < S_;
    float4 q4[16];
    if (act) {
        const float4* qp = (const float4*)(base + (size_t)tid * TD_);
        #pragma unroll
        for (int dd = 0; dd < 16; ++dd) q4[dd] = qp[dd];
    }
    float m = -3.0e38f, lsum = 0.f;
    float acc[64];
    #pragma unroll
    for (int d = 0; d < 64; ++d) acc[d] = 0.f;
    for (int j0 = 0; j0 < S_; j0 += 64) {
        const int tn = min(64, S_ - j0);
        __syncthreads();
        for (int idx = tid; idx < 64 * 64; idx += 320) {
            const int jj = idx >> 6, d = idx & 63;
            const bool ok = jj < tn;
            Ks[jj][d] = ok ? base[(size_t)(j0 + jj) * TD_ + D_ + d] : 0.f;
            Vs[jj][d] = ok ? base[(size_t)(j0 + jj) * TD_ + 2 * D_ + d] : 0.f;
        }
        __syncthreads();
        if (act) {
            const int jmax = CAUSAL ? min(tn, tid - j0 + 1) : tn;
            for (int jj = 0; jj < jmax; ++jj) {
                const float4* kp = (const float4*)Ks[jj];
                float s = 0.f;
                #pragma unroll
                for (int dd = 0; dd < 16; ++dd) {
                    const float4 kv = kp[dd];
                    s += q4[dd].x * kv.x + q4[dd].y * kv.y + q4[dd].z * kv.z + q4[dd].w * kv.w;
                }
                s *= 0.125f;
                float p;
                if (s > m) {
                    const float r = __expf(m - s);
                    lsum *= r;
                    #pragma unroll
                    for (int d = 0; d < 64; ++d) acc[d] *= r;
                    m = s; p = 1.f;
                } else {
                    p = __expf(s - m);
                }
                lsum += p;
                const float4* vp = (const float4*)Vs[jj];
                #pragma unroll
                for (int dd = 0; dd < 16; ++dd) {
                    const float4 vv = vp[dd];
                    acc[dd * 4 + 0] += p * vv.x; acc[dd * 4 + 1] += p * vv.y;
                    acc[dd * 4 + 2] += p * vv.z; acc[dd * 4 + 3] += p * vv.w;
                }
            }
        }
    }
    if (act) {
        const float inv = 1.f / lsum;
        const size_t ob = (size_t)(b * S_ + tid) * D_ + hh * 64;
        #pragma unroll
        for (int d = 0; d < 64; ++d) {
            short sh, sl; split2(acc[d] * inv, sh, sl);
            oh[ob + d] = sh; ol[ob + d] = sl;
        }
    }
}

// ---------------- LayerNorm kernels (block per row, 256 threads) — also emit bf16 split ----------------
__global__ __launch_bounds__(256) void add_ln_kern(float* __restrict__ h, const float* __restrict__ a,
    const float* __restrict__ g, const float* __restrict__ bb,
    short* __restrict__ dh, short* __restrict__ dl)
{
    const int r = blockIdx.x, tid = threadIdx.x;
    const size_t off = (size_t)r * D_;
    const float x0 = h[off + tid] + a[off + tid];
    const float x1 = h[off + tid + 256] + a[off + tid + 256];
    const float2 red = blockReduce2(x0 + x1, x0 * x0 + x1 * x1);
    const float mean = red.x * (1.f / D_);
    const float var = red.y * (1.f / D_) - mean * mean;
    const float rs = rsqrtf(var + 1e-5f);
    const float y0 = (x0 - mean) * rs * g[tid] + bb[tid];
    const float y1 = (x1 - mean) * rs * g[tid + 256] + bb[tid + 256];
    h[off + tid] = y0; h[off + tid + 256] = y1;
    short sh, sl;
    split2(y0, sh, sl); dh[off + tid] = sh;       dl[off + tid] = sl;
    split2(y1, sh, sl); dh[off + tid + 256] = sh; dl[off + tid + 256] = sl;
}

__global__ __launch_bounds__(256) void add2_ln_kern(float* __restrict__ h, const float* __restrict__ moeout,
    const float* __restrict__ g, const float* __restrict__ bb,
    short* __restrict__ dh, short* __restrict__ dl)
{
    const int r = blockIdx.x, tid = threadIdx.x;
    const size_t off = (size_t)r * D_;
    const size_t m0 = (size_t)(2 * r) * D_, m1 = (size_t)(2 * r + 1) * D_;
    const float x0 = h[off + tid]       + moeout[m0 + tid]       + moeout[m1 + tid];
    const float x1 = h[off + tid + 256] + moeout[m0 + tid + 256] + moeout[m1 + tid + 256];
    const float2 red = blockReduce2(x0 + x1, x0 * x0 + x1 * x1);
    const float mean = red.x * (1.f / D_);
    const float var = red.y * (1.f / D_) - mean * mean;
    const float rs = rsqrtf(var + 1e-5f);
    const float y0 = (x0 - mean) * rs * g[tid] + bb[tid];
    const float y1 = (x1 - mean) * rs * g[tid + 256] + bb[tid + 256];
    h[off + tid] = y0; h[off + tid + 256] = y1;
    short sh, sl;
    split2(y0, sh, sl); dh[off + tid] = sh;       dl[off + tid] = sl;
    split2(y1, sh, sl); dh[off + tid + 256] = sh; dl[off + tid + 256] = sl;
}

// final LN: writes ONLY the bf16 split (consumers are GEMMs)
__global__ __launch_bounds__(256) void ln_kern(const float* __restrict__ src,
    const float* __restrict__ g, const float* __restrict__ bb,
    short* __restrict__ dh, short* __restrict__ dl)
{
    const int r = blockIdx.x, tid = threadIdx.x;
    const size_t off = (size_t)r * D_;
    const float x0 = src[off + tid];
    const float x1 = src[off + tid + 256];
    const float2 red = blockReduce2(x0 + x1, x0 * x0 + x1 * x1);
    const float mean = red.x * (1.f / D_);
    const float var = red.y * (1.f / D_) - mean * mean;
    const float rs = rsqrtf(var + 1e-5f);
    const float y0 = (x0 - mean) * rs * g[tid] + bb[tid];
    const float y1 = (x1 - mean) * rs * g[tid + 256] + bb[tid + 256];
    short sh, sl;
    split2(y0, sh, sl); dh[off + tid] = sh;       dl[off + tid] = sl;
    split2(y1, sh, sl); dh[off + tid + 256] = sh; dl[off + tid + 256] = sl;
}

// ---------------- input feature assembly (writes bf16 split, zero-padded K) ----------------
__global__ void assemble_chord_split(const int* __restrict__ x_root, const int* __restrict__ x_attr,
    const float* __restrict__ emb_root, const float* __restrict__ emb_attr,
    const float* __restrict__ fkey, short* __restrict__ dh, short* __restrict__ dl)
{
    const int idx = blockIdx.x * 256 + threadIdx.x;
    if (idx >= R_ * 544) return;
    const int r = idx / 544, k = idx - r * 544;
    float v = 0.f;
    if (k < D_)       v = emb_root[x_root[r] * D_ + k] + emb_attr[x_attr[r] * D_ + k];
    else if (k == D_) v = fkey[r / S_];
    short sh, sl; split2(v, sh, sl);
    dh[idx] = sh; dl[idx] = sl;
}

__global__ void assemble_vis_split(const float* __restrict__ fsem, const float* __restrict__ fscene,
    const float* __restrict__ fmotion, const float* __restrict__ femotion,
    short* __restrict__ dh, short* __restrict__ dl)
{
    const int idx = blockIdx.x * 256 + threadIdx.x;
    if (idx >= R_ * 800) return;
    const int r = idx / 800, k = idx - r * 800;
    float v = 0.f;
    if (k < 768)       v = fsem[(size_t)r * 768 + k];
    else if (k == 768) v = fscene[r];
    else if (k == 769) v = fmotion[r];
    else if (k < 776)  v = femotion[(size_t)r * 6 + (k - 770)];
    short sh, sl; split2(v, sh, sl);
    dh[idx] = sh; dl[idx] = sl;
}

// ---------------- MoE: routing (top-2 of 6, gather lists via atomics) — unchanged ----------------
__global__ __launch_bounds__(256) void moe_route(const float* __restrict__ X,
    const float* __restrict__ gw, const float* __restrict__ gb,
    int* __restrict__ gcnt, int* __restrict__ gtok, float* __restrict__ gwt)
{
    const int t = blockIdx.x * 256 + threadIdx.x;
    if (t >= R_) return;
    float lg[E_];
    #pragma unroll
    for (int e = 0; e < E_; ++e) lg[e] = gb[e];
    const float* xp = X + (size_t)t * D_;
    for (int d = 0; d < D_; ++d) {
        const float xd = xp[d];
        #pragma unroll
        for (int e = 0; e < E_; ++e) lg[e] += xd * gw[e * D_ + d];
    }
    float mx = lg[0];
    #pragma unroll
    for (int e = 1; e < E_; ++e) mx = fmaxf(mx, lg[e]);
    float p[E_];
    #pragma unroll
    for (int e = 0; e < E_; ++e) p[e] = __expf(lg[e] - mx);
    int i1 = 0;
    #pragma unroll
    for (int e = 1; e < E_; ++e) if (p[e] > p[i1]) i1 = e;
    int i2 = (i1 == 0) ? 1 : 0;
    #pragma unroll
    for (int e = 0; e < E_; ++e) if (e != i1 && p[e] > p[i2]) i2 = e;
    const float denom = p[i1] + p[i2];
    const float w1 = p[i1] / denom, w2 = p[i2] / denom;
    int pos1 = atomicAdd(&gcnt[i1], 1);
    gtok[i1 * R_ + pos1] = t * 2;     gwt[i1 * R_ + pos1] = w1;
    int pos2 = atomicAdd(&gcnt[i2], 1);
    gtok[i2 * R_ + pos2] = t * 2 + 1; gwt[i2 * R_ + pos2] = w2;
}

// ---------------- MoE stage A (MFMA): h1 = silu(x@w1+b1)*(x@w2+b2), bf16-split output ----------------
// W1/W2 pre-transposed+split: [E][F][512]. Tile 64 rows x 64 F-cols, 2 waves. grid=(E*MT_, F/64).
__global__ __launch_bounds__(128) void moe_stageA(
    const short* __restrict__ Xh, const short* __restrict__ Xl,
    const short* __restrict__ W1h, const short* __restrict__ W1l,
    const short* __restrict__ W2h, const short* __restrict__ W2l,
    const float* __restrict__ b1, const float* __restrict__ b2,
    const int* __restrict__ gcnt, const int* __restrict__ gtok,
    short* __restrict__ H1h, short* __restrict__ H1l)
{
    const int e = blockIdx.x / MT_, mt = blockIdx.x % MT_;
    const int cnt = gcnt[e];
    const int m0t = mt * 64;
    if (m0t >= cnt) return;
    __shared__ int rid[64];
    __shared__ __align__(16) short Ah[64][40], Al[64][40];
    __shared__ __align__(16) short B1h[64][40], B1l[64][40], B2h[64][40], B2l[64][40];
    const int tid = threadIdx.x;
    if (tid < 64) rid[tid] = (m0t + tid < cnt) ? gtok[e * R_ + m0t + tid] : -1;
    __syncthreads();
    const int f0 = blockIdx.y * 64;
    const int w = tid >> 6, l = tid & 63;
    const facc zero = {0.f, 0.f, 0.f, 0.f};
    facc acc1[4][2], acc2[4][2];
    #pragma unroll
    for (int i = 0; i < 4; ++i)
        #pragma unroll
        for (int j = 0; j < 2; ++j) { acc1[i][j] = zero; acc2[i][j] = zero; }
    const short* sh_ = (w == 0) ? (W1h + ((size_t)e * F_ + f0) * 512) : (W2h + ((size_t)e * F_ + f0) * 512);
    const short* sl_ = (w == 0) ? (W1l + ((size_t)e * F_ + f0) * 512) : (W2l + ((size_t)e * F_ + f0) * 512);
    short (*dsth)[40] = (w == 0) ? B1h : B2h;
    short (*dstl)[40] = (w == 0) ? B1l : B2l;
    const int ar = tid >> 2, aks = (tid & 3) * 8;
    const bfrag zf = {0, 0, 0, 0, 0, 0, 0, 0};
    for (int kc = 0; kc < 512; kc += 32) {
        #pragma unroll
        for (int p = 0; p < 2; ++p) {
            const int row = ar + p * 32;
            const int rr = rid[row];
            if (rr >= 0) {
                const size_t go = (size_t)(rr >> 1) * 512 + kc + aks;
                *(bfrag*)&Ah[row][aks] = *(const bfrag*)&Xh[go];
                *(bfrag*)&Al[row][aks] = *(const bfrag*)&Xl[go];
            } else {
                *(bfrag*)&Ah[row][aks] = zf;
                *(bfrag*)&Al[row][aks] = zf;
            }
        }
        {
            const size_t gb = (size_t)l * 512 + kc;
            #pragma unroll
            for (int i2 = 0; i2 < 4; ++i2) {
                *(bfrag*)&dsth[l][i2 * 8] = *(const bfrag*)&sh_[gb + i2 * 8];
                *(bfrag*)&dstl[l][i2 * 8] = *(const bfrag*)&sl_[gb + i2 * 8];
            }
        }
        __syncthreads();
        bfrag ah[4], al[4];
        #pragma unroll
        for (int i2 = 0; i2 < 4; ++i2) {
            ah[i2] = *(const bfrag*)&Ah[i2 * 16 + (l & 15)][(l >> 4) * 8];
            al[i2] = *(const bfrag*)&Al[i2 * 16 + (l & 15)][(l >> 4) * 8];
        }
        #pragma unroll
        for (int j = 0; j < 2; ++j) {
            const int cc = w * 32 + j * 16 + (l & 15);
            const bfrag b1hf = *(const bfrag*)&B1h[cc][(l >> 4) * 8];
            const bfrag b1lf = *(const bfrag*)&B1l[cc][(l >> 4) * 8];
            const bfrag b2hf = *(const bfrag*)&B2h[cc][(l >> 4) * 8];
            const bfrag b2lf = *(const bfrag*)&B2l[cc][(l >> 4) * 8];
            #pragma unroll
            for (int i2 = 0; i2 < 4; ++i2) {
                acc1[i2][j] = mfma_(ah[i2], b1hf, acc1[i2][j]);
                acc1[i2][j] = mfma_(al[i2], b1hf, acc1[i2][j]);
                acc1[i2][j] = mfma_(ah[i2], b1lf, acc1[i2][j]);
                acc2[i2][j] = mfma_(ah[i2], b2hf, acc2[i2][j]);
                acc2[i2][j] = mfma_(al[i2], b2hf, acc2[i2][j]);
                acc2[i2][j] = mfma_(ah[i2], b2lf, acc2[i2][j]);
            }
        }
        __syncthreads();
    }
    #pragma unroll
    for (int i2 = 0; i2 < 4; ++i2) {
        #pragma unroll
        for (int r = 0; r < 4; ++r) {
            const int mi = i2 * 16 + (l >> 4) * 4 + r;
            const int rr = rid[mi];
            if (rr < 0) continue;
            #pragma unroll
            for (int j = 0; j < 2; ++j) {
                const int f = f0 + w * 32 + j * 16 + (l & 15);
                const float a1 = acc1[i2][j][r] + b1[e * F_ + f];
                const float a2 = acc2[i2][j][r] + b2[e * F_ + f];
                const float hv = (a1 / (1.f + __expf(-a1))) * a2;
                const size_t oi = (size_t)rr * F_ + f;
                short hs, ls; split2(hv, hs, ls);
                H1h[oi] = hs; H1l[oi] = ls;
            }
        }
    }
}

// ---------------- MoE stage B (MFMA): moeout[slot] = wt*(h1@w3 + b3) ----------------
// W3 pre-transposed+split: [E][512][1024]. Tile 64 rows x 128 D-cols. grid=(E*MT_, D/128).
__global__ __launch_bounds__(128) void moe_stageB(
    const short* __restrict__ Xh, const short* __restrict__ Xl,
    const short* __restrict__ W3h, const short* __restrict__ W3l,
    const float* __restrict__ b3,
    const int* __restrict__ gcnt, const int* __restrict__ gtok, const float* __restrict__ gwt,
    float* __restrict__ moeout)
{
    const int e = blockIdx.x / MT_, mt = blockIdx.x % MT_;
    const int cnt = gcnt[e];
    const int m0t = mt * 64;
    if (m0t >= cnt) return;
    __shared__ int rid[64];
    __shared__ float wts[64];
    __shared__ __align__(16) short Ah[64][40], Al[64][40];
    __shared__ __align__(16) short Bh[128][40], Bl[128][40];
    const int tid = threadIdx.x;
    if (tid < 64) {
        rid[tid] = (m0t + tid < cnt) ? gtok[e * R_ + m0t + tid] : -1;
        wts[tid] = (m0t + tid < cnt) ? gwt[e * R_ + m0t + tid] : 0.f;
    }
    __syncthreads();
    const int n0 = blockIdx.y * 128;
    const int w = tid >> 6, l = tid & 63;
    const facc zero = {0.f, 0.f, 0.f, 0.f};
    facc acc[4][4];
    #pragma unroll
    for (int i = 0; i < 4; ++i)
        #pragma unroll
        for (int j = 0; j < 4; ++j) acc[i][j] = zero;
    const int ar = tid >> 2, aks = (tid & 3) * 8;
    const int bcol = tid;
    const size_t bbase = ((size_t)e * 512 + n0 + bcol) * 1024;
    const bfrag zf = {0, 0, 0, 0, 0, 0, 0, 0};
    for (int kc = 0; kc < 1024; kc += 32) {
        #pragma unroll
        for (int p = 0; p < 2; ++p) {
            const int row = ar + p * 32;
            const int rr = rid[row];
            if (rr >= 0) {
                const size_t go = (size_t)rr * F_ + kc + aks;
                *(bfrag*)&Ah[row][aks] = *(const bfrag*)&Xh[go];
                *(bfrag*)&Al[row][aks] = *(const bfrag*)&Xl[go];
            } else {
                *(bfrag*)&Ah[row][aks] = zf;
                *(bfrag*)&Al[row][aks] = zf;
            }
        }
        #pragma unroll
        for (int i2 = 0; i2 < 4; ++i2) {
            *(bfrag*)&Bh[bcol][i2 * 8] = *(const bfrag*)&W3h[bbase + kc + i2 * 8];
            *(bfrag*)&Bl[bcol][i2 * 8] = *(const bfrag*)&W3l[bbase + kc + i2 * 8];
        }
        __syncthreads();
        bfrag ah[4], al[4];
        #pragma unroll
        for (int i2 = 0; i2 < 4; ++i2) {
            ah[i2] = *(const bfrag*)&Ah[i2 * 16 + (l & 15)][(l >> 4) * 8];
            al[i2] = *(const bfrag*)&Al[i2 * 16 + (l & 15)][(l >> 4) * 8];
        }
        #pragma unroll
        for (int j = 0; j < 4; ++j) {
            const int cc = w * 64 + j * 16 + (l & 15);
            const bfrag bh = *(const bfrag*)&Bh[cc][(l >> 4) * 8];
            const bfrag bl = *(const bfrag*)&Bl[cc][(l >> 4) * 8];
            #pragma unroll
            for (int i2 = 0; i2 < 4; ++i2) {
                acc[i2][j] = mfma_(ah[i2], bh, acc[i2][j]);
                acc[i2][j] = mfma_(al[i2], bh, acc[i2][j]);
                acc[i2][j] = mfma_(ah[i2], bl, acc[i2][j]);
            }
        }
        __syncthreads();
    }
    #pragma unroll
    for (int i2 = 0; i2 < 4; ++i2) {
        #pragma unroll
        for (int r = 0; r < 4; ++r) {
            const int mi = i2 * 16 + (l >> 4) * 4 + r;
            const int rr = rid[mi];
            if (rr < 0) continue;
            const float wt = wts[mi];
            #pragma unroll
            for (int j = 0; j < 4; ++j) {
                const int n = n0 + w * 64 + j * 16 + (l & 15);
                moeout[(size_t)rr * D_ + n] = wt * (acc[i2][j][r] + b3[e * D_ + n]);
            }
        }
    }
}

// =========================================================================================
extern "C" void kernel_launch(void* const* d_in, const int* in_sizes, int n_in,
                              void* d_out, int out_size, void* d_ws, size_t ws_size,
                              hipStream_t stream) {
    (void)in_sizes; (void)n_in; (void)out_size; (void)ws_size;
    const int*   x_root    = (const int*)  d_in[1];
    const int*   x_attr    = (const int*)  d_in[2];
    const float* fsem      = (const float*)d_in[3];
    const float* fkey      = (const float*)d_in[4];
    const float* fscene    = (const float*)d_in[5];
    const float* fmotion   = (const float*)d_in[6];
    const float* femotion  = (const float*)d_in[7];
    const float* emb_root  = (const float*)d_in[8];
    const float* emb_attr  = (const float*)d_in[9];
    const float* w_chord   = (const float*)d_in[10];
    const float* b_chord   = (const float*)d_in[11];
    const float* w_vis     = (const float*)d_in[12];
    const float* b_vis     = (const float*)d_in[13];
    const float* pos_c     = (const float*)d_in[14];
    const float* pos_v     = (const float*)d_in[15];
    const float* enc_qkv_w = (const float*)d_in[16];
    const float* enc_qkv_b = (const float*)d_in[17];
    const float* enc_ow    = (const float*)d_in[18];
    const float* enc_ob    = (const float*)d_in[19];
    const float* dec_sqkv_w= (const float*)d_in[20];
    const float* dec_sqkv_b= (const float*)d_in[21];
    const float* dec_sow   = (const float*)d_in[22];
    const float* dec_sob   = (const float*)d_in[23];
    const float* dec_cqkv_w= (const float*)d_in[24];
    const float* dec_cqkv_b= (const float*)d_in[25];
    const float* dec_cow   = (const float*)d_in[26];
    const float* dec_cob   = (const float*)d_in[27];
    const float* enc_gw    = (const float*)d_in[28];
    const float* enc_gb    = (const float*)d_in[29];
    const float* enc_w1    = (const float*)d_in[30];
    const float* enc_b1    = (const float*)d_in[31];
    const float* enc_w2    = (const float*)d_in[32];
    const float* enc_b2    = (const float*)d_in[33];
    const float* enc_w3    = (const float*)d_in[34];
    const float* enc_b3    = (const float*)d_in[35];
    const float* dec_gw    = (const float*)d_in[36];
    const float* dec_gb    = (const float*)d_in[37];
    const float* dec_w1    = (const float*)d_in[38];
    const float* dec_b1    = (const float*)d_in[39];
    const float* dec_w2    = (const float*)d_in[40];
    const float* dec_b2    = (const float*)d_in[41];
    const float* dec_w3    = (const float*)d_in[42];
    const float* dec_b3    = (const float*)d_in[43];
    const float* enc_ln1_g = (const float*)d_in[44];
    const float* enc_ln1_b = (const float*)d_in[45];
    const float* enc_ln2_g = (const float*)d_in[46];
    const float* enc_ln2_b = (const float*)d_in[47];
    const float* dec_ln1_g = (const float*)d_in[48];
    const float* dec_ln1_b = (const float*)d_in[49];
    const float* dec_ln2_g = (const float*)d_in[50];
    const float* dec_ln2_b = (const float*)d_in[51];
    const float* dec_ln3_g = (const float*)d_in[52];
    const float* dec_ln3_b = (const float*)d_in[53];
    const float* enc_fg    = (const float*)d_in[54];
    const float* enc_fb    = (const float*)d_in[55];
    const float* dec_fg    = (const float*)d_in[56];
    const float* dec_fb    = (const float*)d_in[57];
    const float* wout      = (const float*)d_in[58];
    const float* bout      = (const float*)d_in[59];

    // ---- workspace layout (~212 MB) ----
    float* h    = (float*)d_ws;                         // [R][512] f32
    float* qkvb = h + (size_t)R_ * D_;                  // [R][1536] f32 (qkv / proj-out / moeout / assembled splits)
    short* PH   = (short*)(qkvb + (size_t)R_ * TD_);    // [R][512] bf16 hi (activation split)
    short* PL   = PH + (size_t)R_ * D_;
    short* MH   = PL + (size_t)R_ * D_;                 // [R][512] memory (encoder output) split
    short* ML   = MH + (size_t)R_ * D_;
    short* H1H  = ML + (size_t)R_ * D_;                 // [2R][1024] MoE hidden split
    short* H1L  = H1H + (size_t)2 * R_ * F_;
    short* WS0H = H1L + (size_t)2 * R_ * F_;            // weight scratch (4 x WSCAP_ shorts)
    short* WS0L = WS0H + WSCAP_;
    short* WS1H = WS0L + WSCAP_;
    short* WS1L = WS1H + WSCAP_;
    int*   gcnt = (int*)(WS1L + WSCAP_);
    int*   gtok = gcnt + 16;
    float* gwt  = (float*)(gtok + E_ * R_);
    short* AH   = (short*)qkvb;                         // assembled-feature splits live in qkvb region
    short* AL   = AH + (size_t)R_ * 800;

    auto wsplit = [&](const float* src, short* dh, short* dl, int N, int K, int Kp) {
        const int total = N * Kp;
        wsplit_kern<<<dim3((total + 255) / 256), dim3(256), 0, stream>>>(src, dh, dl, N, K, Kp);
    };
    auto tsplit = [&](const float* src, short* dh, short* dl, int K, int N) {
        tsplit_kern<<<dim3(K / 32, N / 32, E_), dim3(256), 0, stream>>>(src, dh, dl, K, N);
    };
    auto gemm = [&](const short* XhP, const short* XlP, int Kp,
                    const short* WhP, const short* WlP,
                    const float* bias, const float* pos,
                    float* Yf, int ldy, int N, short* Yh, short* Yl) {
        gemm_mfma<<<dim3(R_ / 64, (N + 127) / 128), dim3(128), 0, stream>>>(
            XhP, XlP, WhP, WlP, Kp, bias, pos, Yf, ldy, N, Yh, Yl);
    };
    auto run_moe = [&](const float* gw, const float* gb,
                       const float* w1, const float* b1, const float* w2, const float* b2,
                       const float* w3, const float* b3, const float* lng, const float* lnb) {
        hipMemsetAsync(gcnt, 0, 16 * sizeof(int), stream);
        moe_route<<<dim3((R_ + 255) / 256), dim3(256), 0, stream>>>(h, gw, gb, gcnt, gtok, gwt);
        tsplit(w1, WS0H, WS0L, D_, F_);
        tsplit(w2, WS1H, WS1L, D_, F_);
        moe_stageA<<<dim3(E_ * MT_, F_ / 64), dim3(128), 0, stream>>>(
            PH, PL, WS0H, WS0L, WS1H, WS1L, b1, b2, gcnt, gtok, H1H, H1L);
        tsplit(w3, WS0H, WS0L, F_, D_);
        moe_stageB<<<dim3(E_ * MT_, D_ / 128), dim3(128), 0, stream>>>(
            H1H, H1L, WS0H, WS0L, b3, gcnt, gtok, gwt, qkvb);
        add2_ln_kern<<<dim3(R_), dim3(256), 0, stream>>>(h, qkvb, lng, lnb, PH, PL);
    };

    // ---- encoder input: vf = vfc @ w_vis.T + b_vis + pos_v ----
    wsplit(w_vis, WS0H, WS0L, D_, 776, 800);
    assemble_vis_split<<<dim3((R_ * 800 + 255) / 256), dim3(256), 0, stream>>>(
        fsem, fscene, fmotion, femotion, AH, AL);
    gemm(AH, AL, 800, WS0H, WS0L, b_vis, pos_v, h, D_, D_, PH, PL);

    // ---- encoder layers ----
    for (int i = 0; i < L_; ++i) {
        wsplit(enc_qkv_w + (size_t)i * TD_ * D_, WS0H, WS0L, TD_, D_, D_);
        gemm(PH, PL, D_, WS0H, WS0L, enc_qkv_b + (size_t)i * TD_, nullptr, qkvb, TD_, TD_, nullptr, nullptr);
        attn_kern<false><<<dim3(B_ * H_), dim3(320), 0, stream>>>(qkvb, PH, PL);
        wsplit(enc_ow + (size_t)i * D_ * D_, WS0H, WS0L, D_, D_, D_);
        gemm(PH, PL, D_, WS0H, WS0L, enc_ob + (size_t)i * D_, nullptr, qkvb, D_, D_, nullptr, nullptr);
        add_ln_kern<<<dim3(R_), dim3(256), 0, stream>>>(h, qkvb, enc_ln1_g + i * D_, enc_ln1_b + i * D_, PH, PL);
        run_moe(enc_gw + (size_t)i * E_ * D_, enc_gb + (size_t)i * E_,
                enc_w1 + (size_t)i * E_ * D_ * F_, enc_b1 + (size_t)i * E_ * F_,
                enc_w2 + (size_t)i * E_ * D_ * F_, enc_b2 + (size_t)i * E_ * F_,
                enc_w3 + (size_t)i * E_ * F_ * D_, enc_b3 + (size_t)i * E_ * D_,
                enc_ln2_g + i * D_, enc_ln2_b + i * D_);
    }
    ln_kern<<<dim3(R_), dim3(256), 0, stream>>>(h, enc_fg, enc_fb, MH, ML);

    // ---- decoder input: xf = [emb_root+emb_attr | key] @ w_chord.T + b_chord + pos_c ----
    wsplit(w_chord, WS0H, WS0L, D_, 513, 544);
    assemble_chord_split<<<dim3((R_ * 544 + 255) / 256), dim3(256), 0, stream>>>(
        x_root, x_attr, emb_root, emb_attr, fkey, AH, AL);
    gemm(AH, AL, 544, WS0H, WS0L, b_chord, pos_c, h, D_, D_, PH, PL);

    // ---- decoder layers ----
    for (int i = 0; i < L_; ++i) {
        // masked self-attention
        wsplit(dec_sqkv_w + (size_t)i * TD_ * D_, WS0H, WS0L, TD_, D_, D_);
        gemm(PH, PL, D_, WS0H, WS0L, dec_sqkv_b + (size_t)i * TD_, nullptr, qkvb, TD_, TD_, nullptr, nullptr);
        attn_kern<true><<<dim3(B_ * H_), dim3(320), 0, stream>>>(qkvb, PH, PL);
        wsplit(dec_sow + (size_t)i * D_ * D_, WS0H, WS0L, D_, D_, D_);
        gemm(PH, PL, D_, WS0H, WS0L, dec_sob + (size_t)i * D_, nullptr, qkvb, D_, D_, nullptr, nullptr);
        add_ln_kern<<<dim3(R_), dim3(256), 0, stream>>>(h, qkvb, dec_ln1_g + i * D_, dec_ln1_b + i * D_, PH, PL);
        // cross-attention: q from h, k/v from encoder memory
        wsplit(dec_cqkv_w + (size_t)i * TD_ * D_, WS0H, WS0L, TD_, D_, D_);
        gemm(PH, PL, D_, WS0H, WS0L, dec_cqkv_b + (size_t)i * TD_, nullptr, qkvb, TD_, D_, nullptr, nullptr);
        gemm(MH, ML, D_, WS0H + (size_t)D_ * D_, WS0L + (size_t)D_ * D_,
             dec_cqkv_b + (size_t)i * TD_ + D_, nullptr, qkvb + D_, TD_, 2 * D_, nullptr, nullptr);
        attn_kern<false><<<dim3(B_ * H_), dim3(320), 0, stream>>>(qkvb, PH, PL);
        wsplit(dec_cow + (size_t)i * D_ * D_, WS0H, WS0L, D_, D_, D_);
        gemm(PH, PL, D_, WS0H, WS0L, dec_cob + (size_t)i * D_, nullptr, qkvb, D_, D_, nullptr, nullptr);
        add_ln_kern<<<dim3(R_), dim3(256), 0, stream>>>(h, qkvb, dec_ln2_g + i * D_, dec_ln2_b + i * D_, PH, PL);
        // MoE
        run_moe(dec_gw + (size_t)i * E_ * D_, dec_gb + (size_t)i * E_,
                dec_w1 + (size_t)i * E_ * D_ * F_, dec_b1 + (size_t)i * E_ * F_,
                dec_w2 + (size_t)i * E_ * D_ * F_, dec_b2 + (size_t)i * E_ * F_,
                dec_w3 + (size_t)i * E_ * F_ * D_, dec_b3 + (size_t)i * E_ * D_,
                dec_ln3_g + i * D_, dec_ln3_b + i * D_);
    }

    // ---- final LN + output projection (f32 out) ----
    ln_kern<<<dim3(R_), dim3(256), 0, stream>>>(h, dec_fg, dec_fb, PH, PL);
    wsplit(wout, WS0H, WS0L, CHORD_, D_, D_);
    gemm(PH, PL, D_, WS0H, WS0L, bout, nullptr, (float*)d_out, CHORD_, CHORD_, nullptr, nullptr);
}

// Round 2
// 12810.063 us; speedup vs baseline: 1.2111x; 1.2111x over previous
//
#include <hip/hip_runtime.h>

// Problem constants
constexpr int B_ = 32, S_ = 300, D_ = 512, H_ = 8;
constexpr int L_ = 6, E_ = 6, F_ = 1024;
constexpr int CHORD_ = 159;
constexpr int R_ = B_ * S_;      // 9600 rows (tokens)
constexpr int TD_ = 3 * D_;      // 1536
constexpr int MT2_ = R_ / 128;   // 75 row tiles (128-row) per expert worst case
constexpr size_t WSCAP_ = (size_t)E_ * F_ * 512;  // shorts per weight-scratch buffer

typedef short bfrag __attribute__((ext_vector_type(8)));   // 8 bf16 bit-patterns (4 VGPRs)
typedef float facc  __attribute__((ext_vector_type(4)));   // MFMA accumulator

static __device__ __forceinline__ facc mfma_(bfrag a, bfrag b, facc c) {
    return __builtin_amdgcn_mfma_f32_16x16x32_bf16(a, b, c, 0, 0, 0);
}

// float -> bf16 (RNE) bit pattern
static __device__ __forceinline__ short f2bf_rne(float f) {
    unsigned u = __float_as_uint(f);
    return (short)((u + 0x7FFFu + ((u >> 16) & 1u)) >> 16);
}
// split x into hi (truncated bf16) + lo (RNE bf16 of remainder); x ~= hi + lo to ~2^-17 rel
static __device__ __forceinline__ void split2(float x, short& hi, short& lo) {
    unsigned u = __float_as_uint(x);
    hi = (short)(u >> 16);
    float fh = __uint_as_float(u & 0xFFFF0000u);
    lo = f2bf_rne(x - fh);
}

// ---------------- block reduction (sum, sumsq) over 256 threads ----------------
static __device__ __forceinline__ float2 blockReduce2(float s, float ss) {
    __shared__ float red[4][2];
    #pragma unroll
    for (int o = 32; o > 0; o >>= 1) { s += __shfl_down(s, o); ss += __shfl_down(ss, o); }
    const int wid = threadIdx.x >> 6, lane = threadIdx.x & 63;
    if (lane == 0) { red[wid][0] = s; red[wid][1] = ss; }
    __syncthreads();
    if (threadIdx.x == 0) {
        for (int w = 1; w < 4; ++w) { s += red[w][0]; ss += red[w][1]; }
        red[0][0] = s; red[0][1] = ss;
    }
    __syncthreads();
    return make_float2(red[0][0], red[0][1]);
}

// ---------------- weight split (row-major [N][K] f32 -> [N][Kp] bf16 hi/lo, zero pad) ----------------
__global__ void wsplit_kern(const float* __restrict__ src, short* __restrict__ dh, short* __restrict__ dl,
                            int N, int K, int Kp)
{
    const int idx = blockIdx.x * 256 + threadIdx.x;
    if (idx >= N * Kp) return;
    const int n = idx / Kp, k = idx - n * Kp;
    const float v = (k < K) ? src[(size_t)n * K + k] : 0.f;
    short sh, sl; split2(v, sh, sl);
    dh[idx] = sh; dl[idx] = sl;
}

// ---------------- transpose-split: src [E][K][N] f32 -> dst [E][N][K] bf16 hi/lo ----------------
__global__ __launch_bounds__(256) void tsplit_kern(const float* __restrict__ src,
                                                   short* __restrict__ dh, short* __restrict__ dl,
                                                   int K, int N)
{
    __shared__ float tile[32][33];
    const size_t eo = (size_t)blockIdx.z * K * N;
    const float* s = src + eo;
    short* oh = dh + eo;
    short* ol = dl + eo;
    const int kb = blockIdx.x * 32, nb = blockIdx.y * 32;
    const int c = threadIdx.x & 31, r0 = threadIdx.x >> 5;
    #pragma unroll
    for (int p = 0; p < 4; ++p) {
        const int r = r0 + p * 8;
        tile[r][c] = s[(size_t)(kb + r) * N + nb + c];
    }
    __syncthreads();
    #pragma unroll
    for (int p = 0; p < 4; ++p) {
        const int wn = r0 + p * 8;
        const float v = tile[c][wn];
        short sh, sl; split2(v, sh, sl);
        const size_t o = (size_t)(nb + wn) * K + kb + c;
        oh[o] = sh; ol[o] = sl;
    }
}

// ---------------- split-bf16 MFMA GEMM: Y[m,n] = sum_k X[m,k]*W[n,k] + bias (+pos) ----------------
// 128x128 tile, 256 threads (4 waves, each 64x64), BK=32, reg-prefetch pipeline.
__global__ __launch_bounds__(256) void gemm_mfma(
    const short* __restrict__ Xh, const short* __restrict__ Xl,
    const short* __restrict__ Wh, const short* __restrict__ Wl, int Kp,
    const float* __restrict__ bias, const float* __restrict__ pos,
    float* __restrict__ Y, int ldy, int N,
    short* __restrict__ Yh, short* __restrict__ Yl)
{
    __shared__ __align__(16) short Ah[128][40], Al[128][40];
    __shared__ __align__(16) short Bh[128][40], Bl[128][40];
    const int m0 = blockIdx.x * 128, n0 = blockIdx.y * 128;
    const int tid = threadIdx.x;
    const int w = tid >> 6, l = tid & 63;
    const int wr = (w >> 1) * 64, wc = (w & 1) * 64;
    const facc zero = {0.f, 0.f, 0.f, 0.f};
    facc acc[4][4];
    #pragma unroll
    for (int i = 0; i < 4; ++i)
        #pragma unroll
        for (int j = 0; j < 4; ++j) acc[i][j] = zero;
    // A staging: thread covers rows ar & ar+64, k-slot aks
    const int ar = tid >> 2, aks = (tid & 3) * 8;
    // B staging: thread covers col bc, k offsets bk & bk+8
    const int bc = tid >> 1, bk = (tid & 1) * 16;
    const bool bok = (n0 + bc) < N;
    const size_t a0 = (size_t)(m0 + ar) * Kp + aks;
    const size_t a1 = a0 + (size_t)64 * Kp;
    const size_t b0 = (size_t)(n0 + bc) * Kp + bk;
    const bfrag zf = {0, 0, 0, 0, 0, 0, 0, 0};
    bfrag pa0h, pa0l, pa1h, pa1l, pb0h, pb0l, pb1h, pb1l;
    auto LOAD = [&](int kc) {
        pa0h = *(const bfrag*)&Xh[a0 + kc];
        pa0l = *(const bfrag*)&Xl[a0 + kc];
        pa1h = *(const bfrag*)&Xh[a1 + kc];
        pa1l = *(const bfrag*)&Xl[a1 + kc];
        if (bok) {
            pb0h = *(const bfrag*)&Wh[b0 + kc];
            pb0l = *(const bfrag*)&Wl[b0 + kc];
            pb1h = *(const bfrag*)&Wh[b0 + kc + 8];
            pb1l = *(const bfrag*)&Wl[b0 + kc + 8];
        } else { pb0h = zf; pb0l = zf; pb1h = zf; pb1l = zf; }
    };
    LOAD(0);
    for (int kc = 0; kc < Kp; kc += 32) {
        *(bfrag*)&Ah[ar][aks]      = pa0h;  *(bfrag*)&Al[ar][aks]      = pa0l;
        *(bfrag*)&Ah[ar + 64][aks] = pa1h;  *(bfrag*)&Al[ar + 64][aks] = pa1l;
        *(bfrag*)&Bh[bc][bk]       = pb0h;  *(bfrag*)&Bl[bc][bk]       = pb0l;
        *(bfrag*)&Bh[bc][bk + 8]   = pb1h;  *(bfrag*)&Bl[bc][bk + 8]   = pb1l;
        __syncthreads();
        if (kc + 32 < Kp) LOAD(kc + 32);   // prefetch next chunk; latency hides under MFMAs
        bfrag ah[4], al[4];
        #pragma unroll
        for (int i2 = 0; i2 < 4; ++i2) {
            ah[i2] = *(const bfrag*)&Ah[wr + i2 * 16 + (l & 15)][(l >> 4) * 8];
            al[i2] = *(const bfrag*)&Al[wr + i2 * 16 + (l & 15)][(l >> 4) * 8];
        }
        #pragma unroll
        for (int j = 0; j < 4; ++j) {
            const int cc = wc + j * 16 + (l & 15);
            const bfrag bh = *(const bfrag*)&Bh[cc][(l >> 4) * 8];
            const bfrag bl = *(const bfrag*)&Bl[cc][(l >> 4) * 8];
            #pragma unroll
            for (int i2 = 0; i2 < 4; ++i2) {
                acc[i2][j] = mfma_(ah[i2], bh, acc[i2][j]);
                acc[i2][j] = mfma_(al[i2], bh, acc[i2][j]);
                acc[i2][j] = mfma_(ah[i2], bl, acc[i2][j]);
            }
        }
        __syncthreads();
    }
    #pragma unroll
    for (int i2 = 0; i2 < 4; ++i2) {
        #pragma unroll
        for (int r = 0; r < 4; ++r) {
            const int m = m0 + wr + i2 * 16 + (l >> 4) * 4 + r;
            #pragma unroll
            for (int j = 0; j < 4; ++j) {
                const int n = n0 + wc + j * 16 + (l & 15);
                if (n < N) {
                    float y = acc[i2][j][r];
                    if (bias) y += bias[n];
                    if (pos)  y += pos[(size_t)(m % S_) * N + n];
                    Y[(size_t)m * ldy + n] = y;
                    if (Yh) {
                        short sh, sl; split2(y, sh, sl);
                        Yh[(size_t)m * ldy + n] = sh;
                        Yl[(size_t)m * ldy + n] = sl;
                    }
                }
            }
        }
    }
}

// ---------------- fused attention, single-pass online softmax; writes bf16 split output ----------------
template<bool CAUSAL>
__global__ __launch_bounds__(320) void attn_kern(const float* __restrict__ qkv,
                                                 short* __restrict__ oh, short* __restrict__ ol)
{
    __shared__ float Ks[64][64];
    __shared__ float Vs[64][64];
    const int b = blockIdx.x >> 3, hh = blockIdx.x & 7;
    const int tid = threadIdx.x;
    const float* base = qkv + (size_t)b * S_ * TD_ + hh * 64;
    const bool act = tid < S_;
    float4 q4[16];
    if (act) {
        const float4* qp = (const float4*)(base + (size_t)tid * TD_);
        #pragma unroll
        for (int dd = 0; dd < 16; ++dd) q4[dd] = qp[dd];
    }
    float m = -3.0e38f, lsum = 0.f;
    float acc[64];
    #pragma unroll
    for (int d = 0; d < 64; ++d) acc[d] = 0.f;
    for (int j0 = 0; j0 < S_; j0 += 64) {
        const int tn = min(64, S_ - j0);
        __syncthreads();
        for (int idx = tid; idx < 64 * 64; idx += 320) {
            const int jj = idx >> 6, d = idx & 63;
            const bool ok = jj < tn;
            Ks[jj][d] = ok ? base[(size_t)(j0 + jj) * TD_ + D_ + d] : 0.f;
            Vs[jj][d] = ok ? base[(size_t)(j0 + jj) * TD_ + 2 * D_ + d] : 0.f;
        }
        __syncthreads();
        if (act) {
            const int jmax = CAUSAL ? min(tn, tid - j0 + 1) : tn;
            for (int jj = 0; jj < jmax; ++jj) {
                const float4* kp = (const float4*)Ks[jj];
                float s = 0.f;
                #pragma unroll
                for (int dd = 0; dd < 16; ++dd) {
                    const float4 kv = kp[dd];
                    s += q4[dd].x * kv.x + q4[dd].y * kv.y + q4[dd].z * kv.z + q4[dd].w * kv.w;
                }
                s *= 0.125f;
                float p;
                if (s > m) {
                    const float r = __expf(m - s);
                    lsum *= r;
                    #pragma unroll
                    for (int d = 0; d < 64; ++d) acc[d] *= r;
                    m = s; p = 1.f;
                } else {
                    p = __expf(s - m);
                }
                lsum += p;
                const float4* vp = (const float4*)Vs[jj];
                #pragma unroll
                for (int dd = 0; dd < 16; ++dd) {
                    const float4 vv = vp[dd];
                    acc[dd * 4 + 0] += p * vv.x; acc[dd * 4 + 1] += p * vv.y;
                    acc[dd * 4 + 2] += p * vv.z; acc[dd * 4 + 3] += p * vv.w;
                }
            }
        }
    }
    if (act) {
        const float inv = 1.f / lsum;
        const size_t ob = (size_t)(b * S_ + tid) * D_ + hh * 64;
        #pragma unroll
        for (int d = 0; d < 64; ++d) {
            short sh, sl; split2(acc[d] * inv, sh, sl);
            oh[ob + d] = sh; ol[ob + d] = sl;
        }
    }
}

// ---------------- LayerNorm kernels (block per row, 256 threads) — also emit bf16 split ----------------
__global__ __launch_bounds__(256) void add_ln_kern(float* __restrict__ h, const float* __restrict__ a,
    const float* __restrict__ g, const float* __restrict__ bb,
    short* __restrict__ dh, short* __restrict__ dl)
{
    const int r = blockIdx.x, tid = threadIdx.x;
    const size_t off = (size_t)r * D_;
    const float x0 = h[off + tid] + a[off + tid];
    const float x1 = h[off + tid + 256] + a[off + tid + 256];
    const float2 red = blockReduce2(x0 + x1, x0 * x0 + x1 * x1);
    const float mean = red.x * (1.f / D_);
    const float var = red.y * (1.f / D_) - mean * mean;
    const float rs = rsqrtf(var + 1e-5f);
    const float y0 = (x0 - mean) * rs * g[tid] + bb[tid];
    const float y1 = (x1 - mean) * rs * g[tid + 256] + bb[tid + 256];
    h[off + tid] = y0; h[off + tid + 256] = y1;
    short sh, sl;
    split2(y0, sh, sl); dh[off + tid] = sh;       dl[off + tid] = sl;
    split2(y1, sh, sl); dh[off + tid + 256] = sh; dl[off + tid + 256] = sl;
}

__global__ __launch_bounds__(256) void add2_ln_kern(float* __restrict__ h, const float* __restrict__ moeout,
    const float* __restrict__ g, const float* __restrict__ bb,
    short* __restrict__ dh, short* __restrict__ dl)
{
    const int r = blockIdx.x, tid = threadIdx.x;
    const size_t off = (size_t)r * D_;
    const size_t m0 = (size_t)(2 * r) * D_, m1 = (size_t)(2 * r + 1) * D_;
    const float x0 = h[off + tid]       + moeout[m0 + tid]       + moeout[m1 + tid];
    const float x1 = h[off + tid + 256] + moeout[m0 + tid + 256] + moeout[m1 + tid + 256];
    const float2 red = blockReduce2(x0 + x1, x0 * x0 + x1 * x1);
    const float mean = red.x * (1.f / D_);
    const float var = red.y * (1.f / D_) - mean * mean;
    const float rs = rsqrtf(var + 1e-5f);
    const float y0 = (x0 - mean) * rs * g[tid] + bb[tid];
    const float y1 = (x1 - mean) * rs * g[tid + 256] + bb[tid + 256];
    h[off + tid] = y0; h[off + tid + 256] = y1;
    short sh, sl;
    split2(y0, sh, sl); dh[off + tid] = sh;       dl[off + tid] = sl;
    split2(y1, sh, sl); dh[off + tid + 256] = sh; dl[off + tid + 256] = sl;
}

// final LN: writes ONLY the bf16 split (consumers are GEMMs)
__global__ __launch_bounds__(256) void ln_kern(const float* __restrict__ src,
    const float* __restrict__ g, const float* __restrict__ bb,
    short* __restrict__ dh, short* __restrict__ dl)
{
    const int r = blockIdx.x, tid = threadIdx.x;
    const size_t off = (size_t)r * D_;
    const float x0 = src[off + tid];
    const float x1 = src[off + tid + 256];
    const float2 red = blockReduce2(x0 + x1, x0 * x0 + x1 * x1);
    const float mean = red.x * (1.f / D_);
    const float var = red.y * (1.f / D_) - mean * mean;
    const float rs = rsqrtf(var + 1e-5f);
    const float y0 = (x0 - mean) * rs * g[tid] + bb[tid];
    const float y1 = (x1 - mean) * rs * g[tid + 256] + bb[tid + 256];
    short sh, sl;
    split2(y0, sh, sl); dh[off + tid] = sh;       dl[off + tid] = sl;
    split2(y1, sh, sl); dh[off + tid + 256] = sh; dl[off + tid + 256] = sl;
}

// ---------------- input feature assembly (writes bf16 split, zero-padded K) ----------------
__global__ void assemble_chord_split(const int* __restrict__ x_root, const int* __restrict__ x_attr,
    const float* __restrict__ emb_root, const float* __restrict__ emb_attr,
    const float* __restrict__ fkey, short* __restrict__ dh, short* __restrict__ dl)
{
    const int idx = blockIdx.x * 256 + threadIdx.x;
    if (idx >= R_ * 544) return;
    const int r = idx / 544, k = idx - r * 544;
    float v = 0.f;
    if (k < D_)       v = emb_root[x_root[r] * D_ + k] + emb_attr[x_attr[r] * D_ + k];
    else if (k == D_) v = fkey[r / S_];
    short sh, sl; split2(v, sh, sl);
    dh[idx] = sh; dl[idx] = sl;
}

__global__ void assemble_vis_split(const float* __restrict__ fsem, const float* __restrict__ fscene,
    const float* __restrict__ fmotion, const float* __restrict__ femotion,
    short* __restrict__ dh, short* __restrict__ dl)
{
    const int idx = blockIdx.x * 256 + threadIdx.x;
    if (idx >= R_ * 800) return;
    const int r = idx / 800, k = idx - r * 800;
    float v = 0.f;
    if (k < 768)       v = fsem[(size_t)r * 768 + k];
    else if (k == 768) v = fscene[r];
    else if (k == 769) v = fmotion[r];
    else if (k < 776)  v = femotion[(size_t)r * 6 + (k - 770)];
    short sh, sl; split2(v, sh, sl);
    dh[idx] = sh; dl[idx] = sl;
}

// ---------------- MoE: routing (top-2 of 6, gather lists via atomics) ----------------
__global__ __launch_bounds__(256) void moe_route(const float* __restrict__ X,
    const float* __restrict__ gw, const float* __restrict__ gb,
    int* __restrict__ gcnt, int* __restrict__ gtok, float* __restrict__ gwt)
{
    const int t = blockIdx.x * 256 + threadIdx.x;
    if (t >= R_) return;
    float lg[E_];
    #pragma unroll
    for (int e = 0; e < E_; ++e) lg[e] = gb[e];
    const float* xp = X + (size_t)t * D_;
    for (int d = 0; d < D_; ++d) {
        const float xd = xp[d];
        #pragma unroll
        for (int e = 0; e < E_; ++e) lg[e] += xd * gw[e * D_ + d];
    }
    float mx = lg[0];
    #pragma unroll
    for (int e = 1; e < E_; ++e) mx = fmaxf(mx, lg[e]);
    float p[E_];
    #pragma unroll
    for (int e = 0; e < E_; ++e) p[e] = __expf(lg[e] - mx);
    int i1 = 0;
    #pragma unroll
    for (int e = 1; e < E_; ++e) if (p[e] > p[i1]) i1 = e;
    int i2 = (i1 == 0) ? 1 : 0;
    #pragma unroll
    for (int e = 0; e < E_; ++e) if (e != i1 && p[e] > p[i2]) i2 = e;
    const float denom = p[i1] + p[i2];
    const float w1 = p[i1] / denom, w2 = p[i2] / denom;
    int pos1 = atomicAdd(&gcnt[i1], 1);
    gtok[i1 * R_ + pos1] = t * 2;     gwt[i1 * R_ + pos1] = w1;
    int pos2 = atomicAdd(&gcnt[i2], 1);
    gtok[i2 * R_ + pos2] = t * 2 + 1; gwt[i2 * R_ + pos2] = w2;
}

// ---------------- MoE stage A (MFMA): h1 = silu(x@w1+b1)*(x@w2+b2), bf16-split output ----------------
// 128 rows x 64 f (both W1,W2), 256 threads (4 waves: 2 row-halves x 2 f-halves).
__global__ __launch_bounds__(256) void moe_stageA(
    const short* __restrict__ Xh, const short* __restrict__ Xl,
    const short* __restrict__ W1h, const short* __restrict__ W1l,
    const short* __restrict__ W2h, const short* __restrict__ W2l,
    const float* __restrict__ b1, const float* __restrict__ b2,
    const int* __restrict__ gcnt, const int* __restrict__ gtok,
    short* __restrict__ H1h, short* __restrict__ H1l)
{
    const int e = blockIdx.x / MT2_, mt = blockIdx.x % MT2_;
    const int cnt = gcnt[e];
    const int m0t = mt * 128;
    if (m0t >= cnt) return;
    __shared__ int rid[128];
    __shared__ __align__(16) short Ah[128][40], Al[128][40];
    __shared__ __align__(16) short B1h[64][40], B1l[64][40], B2h[64][40], B2l[64][40];
    const int tid = threadIdx.x;
    if (tid < 128) rid[tid] = (m0t + tid < cnt) ? gtok[e * R_ + m0t + tid] : -1;
    __syncthreads();
    const int f0 = blockIdx.y * 64;
    const int w = tid >> 6, l = tid & 63;
    const int wr = (w >> 1) * 64, wf = (w & 1) * 32;
    const facc zero = {0.f, 0.f, 0.f, 0.f};
    facc acc1[4][2], acc2[4][2];
    #pragma unroll
    for (int i = 0; i < 4; ++i)
        #pragma unroll
        for (int j = 0; j < 2; ++j) { acc1[i][j] = zero; acc2[i][j] = zero; }
    // A staging
    const int ar = tid >> 2, aks = (tid & 3) * 8;
    const int r0 = rid[ar], r1 = rid[ar + 64];
    const size_t a0 = (r0 >= 0) ? ((size_t)(r0 >> 1) * 512 + aks) : 0;
    const size_t a1 = (r1 >= 0) ? ((size_t)(r1 >> 1) * 512 + aks) : 0;
    // B staging: wave w stages one of {W1h,W1l,W2h,W2l}, lane covers col c (all 4 k-slots)
    const int c = l;
    const short* bsrc = (w == 0) ? W1h : (w == 1) ? W1l : (w == 2) ? W2h : W2l;
    bsrc += ((size_t)e * F_ + f0 + c) * 512;
    short (*bdst)[40] = (w == 0) ? B1h : (w == 1) ? B1l : (w == 2) ? B2h : B2l;
    const bfrag zf = {0, 0, 0, 0, 0, 0, 0, 0};
    bfrag pa0h, pa0l, pa1h, pa1l, pb0, pb1, pb2, pb3;
    auto LOAD = [&](int kc) {
        pa0h = (r0 >= 0) ? *(const bfrag*)&Xh[a0 + kc] : zf;
        pa0l = (r0 >= 0) ? *(const bfrag*)&Xl[a0 + kc] : zf;
        pa1h = (r1 >= 0) ? *(const bfrag*)&Xh[a1 + kc] : zf;
        pa1l = (r1 >= 0) ? *(const bfrag*)&Xl[a1 + kc] : zf;
        pb0 = *(const bfrag*)&bsrc[kc];
        pb1 = *(const bfrag*)&bsrc[kc + 8];
        pb2 = *(const bfrag*)&bsrc[kc + 16];
        pb3 = *(const bfrag*)&bsrc[kc + 24];
    };
    LOAD(0);
    for (int kc = 0; kc < 512; kc += 32) {
        *(bfrag*)&Ah[ar][aks]      = pa0h;  *(bfrag*)&Al[ar][aks]      = pa0l;
        *(bfrag*)&Ah[ar + 64][aks] = pa1h;  *(bfrag*)&Al[ar + 64][aks] = pa1l;
        *(bfrag*)&bdst[c][0]  = pb0;  *(bfrag*)&bdst[c][8]  = pb1;
        *(bfrag*)&bdst[c][16] = pb2;  *(bfrag*)&bdst[c][24] = pb3;
        __syncthreads();
        if (kc + 32 < 512) LOAD(kc + 32);
        bfrag ah[4], al[4];
        #pragma unroll
        for (int i2 = 0; i2 < 4; ++i2) {
            ah[i2] = *(const bfrag*)&Ah[wr + i2 * 16 + (l & 15)][(l >> 4) * 8];
            al[i2] = *(const bfrag*)&Al[wr + i2 * 16 + (l & 15)][(l >> 4) * 8];
        }
        #pragma unroll
        for (int j = 0; j < 2; ++j) {
            const int fc = wf + j * 16 + (l & 15);
            const bfrag b1hf = *(const bfrag*)&B1h[fc][(l >> 4) * 8];
            const bfrag b1lf = *(const bfrag*)&B1l[fc][(l >> 4) * 8];
            const bfrag b2hf = *(const bfrag*)&B2h[fc][(l >> 4) * 8];
            const bfrag b2lf = *(const bfrag*)&B2l[fc][(l >> 4) * 8];
            #pragma unroll
            for (int i2 = 0; i2 < 4; ++i2) {
                acc1[i2][j] = mfma_(ah[i2], b1hf, acc1[i2][j]);
                acc1[i2][j] = mfma_(al[i2], b1hf, acc1[i2][j]);
                acc1[i2][j] = mfma_(ah[i2], b1lf, acc1[i2][j]);
                acc2[i2][j] = mfma_(ah[i2], b2hf, acc2[i2][j]);
                acc2[i2][j] = mfma_(al[i2], b2hf, acc2[i2][j]);
                acc2[i2][j] = mfma_(ah[i2], b2lf, acc2[i2][j]);
            }
        }
        __syncthreads();
    }
    #pragma unroll
    for (int i2 = 0; i2 < 4; ++i2) {
        #pragma unroll
        for (int r = 0; r < 4; ++r) {
            const int mi = wr + i2 * 16 + (l >> 4) * 4 + r;
            const int rr = rid[mi];
            if (rr < 0) continue;
            #pragma unroll
            for (int j = 0; j < 2; ++j) {
                const int f = f0 + wf + j * 16 + (l & 15);
                const float a1v = acc1[i2][j][r] + b1[e * F_ + f];
                const float a2v = acc2[i2][j][r] + b2[e * F_ + f];
                const float hv = (a1v / (1.f + __expf(-a1v))) * a2v;
                const size_t oi = (size_t)rr * F_ + f;
                short hs, ls; split2(hv, hs, ls);
                H1h[oi] = hs; H1l[oi] = ls;
            }
        }
    }
}

// ---------------- MoE stage B (MFMA): moeout[slot] = wt*(h1@w3 + b3) ----------------
// 128 rows x 128 D-cols, 256 threads. W3 pre-transposed+split: [E][512][1024].
__global__ __launch_bounds__(256) void moe_stageB(
    const short* __restrict__ Xh, const short* __restrict__ Xl,
    const short* __restrict__ W3h, const short* __restrict__ W3l,
    const float* __restrict__ b3,
    const int* __restrict__ gcnt, const int* __restrict__ gtok, const float* __restrict__ gwt,
    float* __restrict__ moeout)
{
    const int e = blockIdx.x / MT2_, mt = blockIdx.x % MT2_;
    const int cnt = gcnt[e];
    const int m0t = mt * 128;
    if (m0t >= cnt) return;
    __shared__ int rid[128];
    __shared__ float wts[128];
    __shared__ __align__(16) short Ah[128][40], Al[128][40];
    __shared__ __align__(16) short Bh[128][40], Bl[128][40];
    const int tid = threadIdx.x;
    if (tid < 128) {
        rid[tid] = (m0t + tid < cnt) ? gtok[e * R_ + m0t + tid] : -1;
        wts[tid] = (m0t + tid < cnt) ? gwt[e * R_ + m0t + tid] : 0.f;
    }
    __syncthreads();
    const int n0 = blockIdx.y * 128;
    const int w = tid >> 6, l = tid & 63;
    const int wr = (w >> 1) * 64, wc = (w & 1) * 64;
    const facc zero = {0.f, 0.f, 0.f, 0.f};
    facc acc[4][4];
    #pragma unroll
    for (int i = 0; i < 4; ++i)
        #pragma unroll
        for (int j = 0; j < 4; ++j) acc[i][j] = zero;
    const int ar = tid >> 2, aks = (tid & 3) * 8;
    const int r0 = rid[ar], r1 = rid[ar + 64];
    const size_t a0 = (r0 >= 0) ? ((size_t)r0 * F_ + aks) : 0;
    const size_t a1 = (r1 >= 0) ? ((size_t)r1 * F_ + aks) : 0;
    const int bc = tid >> 1, bk = (tid & 1) * 16;
    const size_t b0 = ((size_t)e * 512 + n0 + bc) * 1024 + bk;
    const bfrag zf = {0, 0, 0, 0, 0, 0, 0, 0};
    bfrag pa0h, pa0l, pa1h, pa1l, pb0h, pb0l, pb1h, pb1l;
    auto LOAD = [&](int kc) {
        pa0h = (r0 >= 0) ? *(const bfrag*)&Xh[a0 + kc] : zf;
        pa0l = (r0 >= 0) ? *(const bfrag*)&Xl[a0 + kc] : zf;
        pa1h = (r1 >= 0) ? *(const bfrag*)&Xh[a1 + kc] : zf;
        pa1l = (r1 >= 0) ? *(const bfrag*)&Xl[a1 + kc] : zf;
        pb0h = *(const bfrag*)&W3h[b0 + kc];
        pb0l = *(const bfrag*)&W3l[b0 + kc];
        pb1h = *(const bfrag*)&W3h[b0 + kc + 8];
        pb1l = *(const bfrag*)&W3l[b0 + kc + 8];
    };
    LOAD(0);
    for (int kc = 0; kc < 1024; kc += 32) {
        *(bfrag*)&Ah[ar][aks]      = pa0h;  *(bfrag*)&Al[ar][aks]      = pa0l;
        *(bfrag*)&Ah[ar + 64][aks] = pa1h;  *(bfrag*)&Al[ar + 64][aks] = pa1l;
        *(bfrag*)&Bh[bc][bk]       = pb0h;  *(bfrag*)&Bl[bc][bk]       = pb0l;
        *(bfrag*)&Bh[bc][bk + 8]   = pb1h;  *(bfrag*)&Bl[bc][bk + 8]   = pb1l;
        __syncthreads();
        if (kc + 32 < 1024) LOAD(kc + 32);
        bfrag ah[4], al[4];
        #pragma unroll
        for (int i2 = 0; i2 < 4; ++i2) {
            ah[i2] = *(const bfrag*)&Ah[wr + i2 * 16 + (l & 15)][(l >> 4) * 8];
            al[i2] = *(const bfrag*)&Al[wr + i2 * 16 + (l & 15)][(l >> 4) * 8];
        }
        #pragma unroll
        for (int j = 0; j < 4; ++j) {
            const int cc = wc + j * 16 + (l & 15);
            const bfrag bh = *(const bfrag*)&Bh[cc][(l >> 4) * 8];
            const bfrag bl = *(const bfrag*)&Bl[cc][(l >> 4) * 8];
            #pragma unroll
            for (int i2 = 0; i2 < 4; ++i2) {
                acc[i2][j] = mfma_(ah[i2], bh, acc[i2][j]);
                acc[i2][j] = mfma_(al[i2], bh, acc[i2][j]);
                acc[i2][j] = mfma_(ah[i2], bl, acc[i2][j]);
            }
        }
        __syncthreads();
    }
    #pragma unroll
    for (int i2 = 0; i2 < 4; ++i2) {
        #pragma unroll
        for (int r = 0; r < 4; ++r) {
            const int mi = wr + i2 * 16 + (l >> 4) * 4 + r;
            const int rr = rid[mi];
            if (rr < 0) continue;
            const float wt = wts[mi];
            #pragma unroll
            for (int j = 0; j < 4; ++j) {
                const int n = n0 + wc + j * 16 + (l & 15);
                moeout[(size_t)rr * D_ + n] = wt * (acc[i2][j][r] + b3[e * D_ + n]);
            }
        }
    }
}

// =========================================================================================
extern "C" void kernel_launch(void* const* d_in, const int* in_sizes, int n_in,
                              void* d_out, int out_size, void* d_ws, size_t ws_size,
                              hipStream_t stream) {
    (void)in_sizes; (void)n_in; (void)out_size; (void)ws_size;
    const int*   x_root    = (const int*)  d_in[1];
    const int*   x_attr    = (const int*)  d_in[2];
    const float* fsem      = (const float*)d_in[3];
    const float* fkey      = (const float*)d_in[4];
    const float* fscene    = (const float*)d_in[5];
    const float* fmotion   = (const float*)d_in[6];
    const float* femotion  = (const float*)d_in[7];
    const float* emb_root  = (const float*)d_in[8];
    const float* emb_attr  = (const float*)d_in[9];
    const float* w_chord   = (const float*)d_in[10];
    const float* b_chord   = (const float*)d_in[11];
    const float* w_vis     = (const float*)d_in[12];
    const float* b_vis     = (const float*)d_in[13];
    const float* pos_c     = (const float*)d_in[14];
    const float* pos_v     = (const float*)d_in[15];
    const float* enc_qkv_w = (const float*)d_in[16];
    const float* enc_qkv_b = (const float*)d_in[17];
    const float* enc_ow    = (const float*)d_in[18];
    const float* enc_ob    = (const float*)d_in[19];
    const float* dec_sqkv_w= (const float*)d_in[20];
    const float* dec_sqkv_b= (const float*)d_in[21];
    const float* dec_sow   = (const float*)d_in[22];
    const float* dec_sob   = (const float*)d_in[23];
    const float* dec_cqkv_w= (const float*)d_in[24];
    const float* dec_cqkv_b= (const float*)d_in[25];
    const float* dec_cow   = (const float*)d_in[26];
    const float* dec_cob   = (const float*)d_in[27];
    const float* enc_gw    = (const float*)d_in[28];
    const float* enc_gb    = (const float*)d_in[29];
    const float* enc_w1    = (const float*)d_in[30];
    const float* enc_b1    = (const float*)d_in[31];
    const float* enc_w2    = (const float*)d_in[32];
    const float* enc_b2    = (const float*)d_in[33];
    const float* enc_w3    = (const float*)d_in[34];
    const float* enc_b3    = (const float*)d_in[35];
    const float* dec_gw    = (const float*)d_in[36];
    const float* dec_gb    = (const float*)d_in[37];
    const float* dec_w1    = (const float*)d_in[38];
    const float* dec_b1    = (const float*)d_in[39];
    const float* dec_w2    = (const float*)d_in[40];
    const float* dec_b2    = (const float*)d_in[41];
    const float* dec_w3    = (const float*)d_in[42];
    const float* dec_b3    = (const float*)d_in[43];
    const float* enc_ln1_g = (const float*)d_in[44];
    const float* enc_ln1_b = (const float*)d_in[45];
    const float* enc_ln2_g = (const float*)d_in[46];
    const float* enc_ln2_b = (const float*)d_in[47];
    const float* dec_ln1_g = (const float*)d_in[48];
    const float* dec_ln1_b = (const float*)d_in[49];
    const float* dec_ln2_g = (const float*)d_in[50];
    const float* dec_ln2_b = (const float*)d_in[51];
    const float* dec_ln3_g = (const float*)d_in[52];
    const float* dec_ln3_b = (const float*)d_in[53];
    const float* enc_fg    = (const float*)d_in[54];
    const float* enc_fb    = (const float*)d_in[55];
    const float* dec_fg    = (const float*)d_in[56];
    const float* dec_fb    = (const float*)d_in[57];
    const float* wout      = (const float*)d_in[58];
    const float* bout      = (const float*)d_in[59];

    // ---- workspace layout (~212 MB) ----
    float* h    = (float*)d_ws;                         // [R][512] f32
    float* qkvb = h + (size_t)R_ * D_;                  // [R][1536] f32
    short* PH   = (short*)(qkvb + (size_t)R_ * TD_);    // [R][512] bf16 hi (activation split)
    short* PL   = PH + (size_t)R_ * D_;
    short* MH   = PL + (size_t)R_ * D_;                 // [R][512] memory (encoder output) split
    short* ML   = MH + (size_t)R_ * D_;
    short* H1H  = ML + (size_t)R_ * D_;                 // [2R][1024] MoE hidden split
    short* H1L  = H1H + (size_t)2 * R_ * F_;
    short* WS0H = H1L + (size_t)2 * R_ * F_;            // weight scratch (4 x WSCAP_ shorts)
    short* WS0L = WS0H + WSCAP_;
    short* WS1H = WS0L + WSCAP_;
    short* WS1L = WS1H + WSCAP_;
    int*   gcnt = (int*)(WS1L + WSCAP_);
    int*   gtok = gcnt + 16;
    float* gwt  = (float*)(gtok + E_ * R_);
    short* AH   = (short*)qkvb;                         // assembled-feature splits live in qkvb region
    short* AL   = AH + (size_t)R_ * 800;

    auto wsplit = [&](const float* src, short* dh, short* dl, int N, int K, int Kp) {
        const int total = N * Kp;
        wsplit_kern<<<dim3((total + 255) / 256), dim3(256), 0, stream>>>(src, dh, dl, N, K, Kp);
    };
    auto tsplit = [&](const float* src, short* dh, short* dl, int K, int N) {
        tsplit_kern<<<dim3(K / 32, N / 32, E_), dim3(256), 0, stream>>>(src, dh, dl, K, N);
    };
    auto gemm = [&](const short* XhP, const short* XlP, int Kp,
                    const short* WhP, const short* WlP,
                    const float* bias, const float* pos,
                    float* Yf, int ldy, int N, short* Yh, short* Yl) {
        gemm_mfma<<<dim3(R_ / 128, (N + 127) / 128), dim3(256), 0, stream>>>(
            XhP, XlP, WhP, WlP, Kp, bias, pos, Yf, ldy, N, Yh, Yl);
    };
    auto run_moe = [&](const float* gw, const float* gb,
                       const float* w1, const float* b1, const float* w2, const float* b2,
                       const float* w3, const float* b3, const float* lng, const float* lnb) {
        hipMemsetAsync(gcnt, 0, 16 * sizeof(int), stream);
        moe_route<<<dim3((R_ + 255) / 256), dim3(256), 0, stream>>>(h, gw, gb, gcnt, gtok, gwt);
        tsplit(w1, WS0H, WS0L, D_, F_);
        tsplit(w2, WS1H, WS1L, D_, F_);
        moe_stageA<<<dim3(E_ * MT2_, F_ / 64), dim3(256), 0, stream>>>(
            PH, PL, WS0H, WS0L, WS1H, WS1L, b1, b2, gcnt, gtok, H1H, H1L);
        tsplit(w3, WS0H, WS0L, F_, D_);
        moe_stageB<<<dim3(E_ * MT2_, D_ / 128), dim3(256), 0, stream>>>(
            H1H, H1L, WS0H, WS0L, b3, gcnt, gtok, gwt, qkvb);
        add2_ln_kern<<<dim3(R_), dim3(256), 0, stream>>>(h, qkvb, lng, lnb, PH, PL);
    };

    // ---- encoder input: vf = vfc @ w_vis.T + b_vis + pos_v ----
    wsplit(w_vis, WS0H, WS0L, D_, 776, 800);
    assemble_vis_split<<<dim3((R_ * 800 + 255) / 256), dim3(256), 0, stream>>>(
        fsem, fscene, fmotion, femotion, AH, AL);
    gemm(AH, AL, 800, WS0H, WS0L, b_vis, pos_v, h, D_, D_, PH, PL);

    // ---- encoder layers ----
    for (int i = 0; i < L_; ++i) {
        wsplit(enc_qkv_w + (size_t)i * TD_ * D_, WS0H, WS0L, TD_, D_, D_);
        gemm(PH, PL, D_, WS0H, WS0L, enc_qkv_b + (size_t)i * TD_, nullptr, qkvb, TD_, TD_, nullptr, nullptr);
        attn_kern<false><<<dim3(B_ * H_), dim3(320), 0, stream>>>(qkvb, PH, PL);
        wsplit(enc_ow + (size_t)i * D_ * D_, WS0H, WS0L, D_, D_, D_);
        gemm(PH, PL, D_, WS0H, WS0L, enc_ob + (size_t)i * D_, nullptr, qkvb, D_, D_, nullptr, nullptr);
        add_ln_kern<<<dim3(R_), dim3(256), 0, stream>>>(h, qkvb, enc_ln1_g + i * D_, enc_ln1_b + i * D_, PH, PL);
        run_moe(enc_gw + (size_t)i * E_ * D_, enc_gb + (size_t)i * E_,
                enc_w1 + (size_t)i * E_ * D_ * F_, enc_b1 + (size_t)i * E_ * F_,
                enc_w2 + (size_t)i * E_ * D_ * F_, enc_b2 + (size_t)i * E_ * F_,
                enc_w3 + (size_t)i * E_ * F_ * D_, enc_b3 + (size_t)i * E_ * D_,
                enc_ln2_g + i * D_, enc_ln2_b + i * D_);
    }
    ln_kern<<<dim3(R_), dim3(256), 0, stream>>>(h, enc_fg, enc_fb, MH, ML);

    // ---- decoder input: xf = [emb_root+emb_attr | key] @ w_chord.T + b_chord + pos_c ----
    wsplit(w_chord, WS0H, WS0L, D_, 513, 544);
    assemble_chord_split<<<dim3((R_ * 544 + 255) / 256), dim3(256), 0, stream>>>(
        x_root, x_attr, emb_root, emb_attr, fkey, AH, AL);
    gemm(AH, AL, 544, WS0H, WS0L, b_chord, pos_c, h, D_, D_, PH, PL);

    // ---- decoder layers ----
    for (int i = 0; i < L_; ++i) {
        // masked self-attention
        wsplit(dec_sqkv_w + (size_t)i * TD_ * D_, WS0H, WS0L, TD_, D_, D_);
        gemm(PH, PL, D_, WS0H, WS0L, dec_sqkv_b + (size_t)i * TD_, nullptr, qkvb, TD_, TD_, nullptr, nullptr);
        attn_kern<true><<<dim3(B_ * H_), dim3(320), 0, stream>>>(qkvb, PH, PL);
        wsplit(dec_sow + (size_t)i * D_ * D_, WS0H, WS0L, D_, D_, D_);
        gemm(PH, PL, D_, WS0H, WS0L, dec_sob + (size_t)i * D_, nullptr, qkvb, D_, D_, nullptr, nullptr);
        add_ln_kern<<<dim3(R_), dim3(256), 0, stream>>>(h, qkvb, dec_ln1_g + i * D_, dec_ln1_b + i * D_, PH, PL);
        // cross-attention: q from h, k/v from encoder memory
        wsplit(dec_cqkv_w + (size_t)i * TD_ * D_, WS0H, WS0L, TD_, D_, D_);
        gemm(PH, PL, D_, WS0H, WS0L, dec_cqkv_b + (size_t)i * TD_, nullptr, qkvb, TD_, D_, nullptr, nullptr);
        gemm(MH, ML, D_, WS0H + (size_t)D_ * D_, WS0L + (size_t)D_ * D_,
             dec_cqkv_b + (size_t)i * TD_ + D_, nullptr, qkvb + D_, TD_, 2 * D_, nullptr, nullptr);
        attn_kern<false><<<dim3(B_ * H_), dim3(320), 0, stream>>>(qkvb, PH, PL);
        wsplit(dec_cow + (size_t)i * D_ * D_, WS0H, WS0L, D_, D_, D_);
        gemm(PH, PL, D_, WS0H, WS0L, dec_cob + (size_t)i * D_, nullptr, qkvb, D_, D_, nullptr, nullptr);
        add_ln_kern<<<dim3(R_), dim3(256), 0, stream>>>(h, qkvb, dec_ln2_g + i * D_, dec_ln2_b + i * D_, PH, PL);
        // MoE
        run_moe(dec_gw + (size_t)i * E_ * D_, dec_gb + (size_t)i * E_,
                dec_w1 + (size_t)i * E_ * D_ * F_, dec_b1 + (size_t)i * E_ * F_,
                dec_w2 + (size_t)i * E_ * D_ * F_, dec_b2 + (size_t)i * E_ * F_,
                dec_w3 + (size_t)i * E_ * F_ * D_, dec_b3 + (size_t)i * E_ * D_,
                dec_ln3_g + i * D_, dec_ln3_b + i * D_);
    }

    // ---- final LN + output projection (f32 out) ----
    ln_kern<<<dim3(R_), dim3(256), 0, stream>>>(h, dec_fg, dec_fb, PH, PL);
    wsplit(wout, WS0H, WS0L, CHORD_, D_, D_);
    gemm(PH, PL, D_, WS0H, WS0L, bout, nullptr, (float*)d_out, CHORD_, CHORD_, nullptr, nullptr);
}